// Round 1
// baseline (1153.277 us; speedup 1.0000x reference)
//
#include <hip/hip_runtime.h>

// EnhanceSelfAttention: B=16, N=577, C=768, H=12, d=64, fp32.
// R1 baseline: fp32 everywhere (correctness anchor + counter baseline).
//   K1: qkv = x @ qkv_w + qkv_b  -> q,k,v in (B,H,N,d)
//   K2: flash-style causal attention with rel-pos bias -> attn_out (B,N,C)
//   K3: out = attn_out @ out_w + out_b

#define BATCH 16
#define SEQ   577
#define CH    768
#define NH    12
#define HD    64
#define MROWS (BATCH*SEQ)   // 9232
#define NRD   2212          // (2*24-1)^2 + 3
#define SCALE 0.125f        // 64^-0.5

// ---------------- K1: QKV GEMM (M=9232, K=768, N=2304) ----------------
__global__ __launch_bounds__(256) void qkv_gemm_k(
    const float* __restrict__ x, const float* __restrict__ w,
    const float* __restrict__ bias,
    float* __restrict__ qout, float* __restrict__ kout, float* __restrict__ vout)
{
    __shared__ float As[16][68];
    __shared__ float Bs[16][68];
    const int t  = threadIdx.x;
    const int tx = t & 15, ty = t >> 4;
    const int m0 = blockIdx.y * 64;
    const int n0 = blockIdx.x * 64;
    float acc[4][4] = {};
    for (int k0 = 0; k0 < CH; k0 += 16) {
        #pragma unroll
        for (int i = 0; i < 4; ++i) {
            int idx = t + i * 256;
            int mm = idx >> 4, kk = idx & 15;
            int gm = m0 + mm;
            As[kk][mm] = (gm < MROWS) ? x[(size_t)gm * CH + k0 + kk] : 0.f;
        }
        #pragma unroll
        for (int i = 0; i < 4; ++i) {
            int idx = t + i * 256;
            int kk = idx >> 6, nn = idx & 63;
            Bs[kk][nn] = w[(size_t)(k0 + kk) * (3 * CH) + n0 + nn];
        }
        __syncthreads();
        #pragma unroll
        for (int kk = 0; kk < 16; ++kk) {
            float4 a = *(const float4*)&As[kk][ty * 4];
            float4 b = *(const float4*)&Bs[kk][tx * 4];
            float av[4] = {a.x, a.y, a.z, a.w};
            float bv[4] = {b.x, b.y, b.z, b.w};
            #pragma unroll
            for (int i = 0; i < 4; ++i)
                #pragma unroll
                for (int j = 0; j < 4; ++j)
                    acc[i][j] = fmaf(av[i], bv[j], acc[i][j]);
        }
        __syncthreads();
    }
    // Each 64-wide column block maps to exactly one (i3, head) since d=64.
    const int i3 = n0 / CH;
    const int h  = (n0 % CH) / HD;
    float* dst = (i3 == 0) ? qout : ((i3 == 1) ? kout : vout);
    #pragma unroll
    for (int i = 0; i < 4; ++i) {
        int gm = m0 + ty * 4 + i;
        if (gm < MROWS) {
            int b = gm / SEQ, n = gm % SEQ;
            float* row = dst + ((size_t)(b * NH + h) * SEQ + n) * HD;
            #pragma unroll
            for (int j = 0; j < 4; ++j) {
                int dd = tx * 4 + j;
                row[dd] = acc[i][j] + bias[n0 + dd];
            }
        }
    }
}

// ---------------- K2: flash attention with rel-pos bias + causal mask ----------------
// grid (10, 192): x = q-row block (64 rows), y = b*H+h. 256 threads, 4x4 microtiles.
__global__ __launch_bounds__(256) void attn_k(
    const float* __restrict__ qg, const float* __restrict__ kg, const float* __restrict__ vg,
    const float* __restrict__ pos_emb, const int* __restrict__ rel_index,
    float* __restrict__ out)
{
    __shared__ float Qs[64][68];
    __shared__ float KVs[64][68];   // time-shared: K for S-phase, V for PV-phase
    __shared__ float Ss[64][68];
    __shared__ float pe[NRD];
    __shared__ float pmax[64][4];
    __shared__ float psum[64][4];
    __shared__ float rowm[64];
    __shared__ float rowf[64];
    __shared__ float rowl[64];

    const int qb = blockIdx.x;          // 0..9
    const int bh = blockIdx.y;          // 0..191
    const int b = bh / NH, h = bh % NH;
    const int t  = threadIdx.x;
    const int tx = t & 15, ty = t >> 4;
    const int q0 = qb * 64;

    const float* qbase = qg + (size_t)(b * NH + h) * SEQ * HD;
    const float* kbase = kg + (size_t)(b * NH + h) * SEQ * HD;
    const float* vbase = vg + (size_t)(b * NH + h) * SEQ * HD;

    for (int i = t; i < NRD; i += 256) pe[i] = pos_emb[(size_t)h * NRD + i];

    #pragma unroll
    for (int i = 0; i < 16; ++i) {
        int idx = t + i * 256;
        int r = idx >> 6, d = idx & 63;
        int row = q0 + r;
        Qs[r][d] = (row < SEQ) ? qbase[(size_t)row * HD + d] : 0.f;
    }

    float o[4][4] = {};
    float m_reg = -3.0e38f, l_reg = 0.f;   // live in threads t<64 only

    for (int kb = 0; kb <= qb; ++kb) {
        const int k0 = kb * 64;
        __syncthreads();   // prev iter's Ss/KVs fully consumed
        // load K tile
        #pragma unroll
        for (int i = 0; i < 16; ++i) {
            int idx = t + i * 256;
            int r = idx >> 6, d = idx & 63;
            int row = k0 + r;
            KVs[r][d] = (row < SEQ) ? kbase[(size_t)row * HD + d] : 0.f;
        }
        __syncthreads();
        // S = Q K^T
        float s[4][4] = {};
        #pragma unroll 4
        for (int d4 = 0; d4 < 64; d4 += 4) {
            float4 a[4], bb[4];
            #pragma unroll
            for (int i = 0; i < 4; ++i) a[i]  = *(const float4*)&Qs[ty * 4 + i][d4];
            #pragma unroll
            for (int j = 0; j < 4; ++j) bb[j] = *(const float4*)&KVs[tx * 4 + j][d4];
            #pragma unroll
            for (int i = 0; i < 4; ++i) {
                #pragma unroll
                for (int j = 0; j < 4; ++j) {
                    s[i][j] = fmaf(a[i].x, bb[j].x, s[i][j]);
                    s[i][j] = fmaf(a[i].y, bb[j].y, s[i][j]);
                    s[i][j] = fmaf(a[i].z, bb[j].z, s[i][j]);
                    s[i][j] = fmaf(a[i].w, bb[j].w, s[i][j]);
                }
            }
        }
        // scale + rel-pos bias + causal mask -> Ss
        #pragma unroll
        for (int i = 0; i < 4; ++i) {
            int qrow = q0 + ty * 4 + i;
            #pragma unroll
            for (int j = 0; j < 4; ++j) {
                int kcol = k0 + tx * 4 + j;
                float val;
                if (qrow < SEQ && kcol < SEQ && kcol <= qrow) {
                    int ridx = rel_index[(size_t)qrow * SEQ + kcol];
                    val = s[i][j] * SCALE + pe[ridx];
                } else {
                    val = -65504.f;
                }
                Ss[ty * 4 + i][tx * 4 + j] = val;
            }
        }
        __syncthreads();
        // load V tile (overlapped with softmax phases; consumed only after 3 barriers)
        #pragma unroll
        for (int i = 0; i < 16; ++i) {
            int idx = t + i * 256;
            int r = idx >> 6, d = idx & 63;
            int row = k0 + r;
            KVs[r][d] = (row < SEQ) ? vbase[(size_t)row * HD + d] : 0.f;
        }
        // softmax phase 1: segment max (4 segments of 16 per row)
        {
            int row = t & 63, seg = t >> 6;
            float pm = -3.0e38f;
            #pragma unroll
            for (int c4 = 0; c4 < 4; ++c4) {
                float4 v4 = *(const float4*)&Ss[row][seg * 16 + c4 * 4];
                pm = fmaxf(pm, fmaxf(fmaxf(v4.x, v4.y), fmaxf(v4.z, v4.w)));
            }
            pmax[row][seg] = pm;
        }
        __syncthreads();
        // phase 2: new running max + rescale factor
        if (t < 64) {
            float bm = fmaxf(fmaxf(pmax[t][0], pmax[t][1]), fmaxf(pmax[t][2], pmax[t][3]));
            float mn = fmaxf(m_reg, bm);
            float f  = __expf(m_reg - mn);
            m_reg = mn;
            l_reg *= f;
            rowm[t] = mn;
            rowf[t] = f;
        }
        __syncthreads();
        // phase 3: exponentiate + segment sums
        {
            int row = t & 63, seg = t >> 6;
            float mn = rowm[row];
            float sum = 0.f;
            #pragma unroll
            for (int c4 = 0; c4 < 4; ++c4) {
                float4 v4 = *(const float4*)&Ss[row][seg * 16 + c4 * 4];
                v4.x = __expf(v4.x - mn); v4.y = __expf(v4.y - mn);
                v4.z = __expf(v4.z - mn); v4.w = __expf(v4.w - mn);
                *(float4*)&Ss[row][seg * 16 + c4 * 4] = v4;
                sum += v4.x + v4.y + v4.z + v4.w;
            }
            psum[row][seg] = sum;
        }
        __syncthreads();
        // phase 4: running denominator
        if (t < 64) {
            l_reg += psum[t][0] + psum[t][1] + psum[t][2] + psum[t][3];
        }
        // rescale O, then PV accumulate
        float fr[4];
        #pragma unroll
        for (int i = 0; i < 4; ++i) fr[i] = rowf[ty * 4 + i];
        #pragma unroll
        for (int i = 0; i < 4; ++i)
            #pragma unroll
            for (int j = 0; j < 4; ++j) o[i][j] *= fr[i];
        #pragma unroll 4
        for (int c4 = 0; c4 < 64; c4 += 4) {
            float4 p[4], vv[4];
            #pragma unroll
            for (int i = 0; i < 4; ++i)  p[i]  = *(const float4*)&Ss[ty * 4 + i][c4];
            #pragma unroll
            for (int cc = 0; cc < 4; ++cc) vv[cc] = *(const float4*)&KVs[c4 + cc][tx * 4];
            #pragma unroll
            for (int i = 0; i < 4; ++i) {
                float pi[4] = {p[i].x, p[i].y, p[i].z, p[i].w};
                #pragma unroll
                for (int cc = 0; cc < 4; ++cc) {
                    o[i][0] = fmaf(pi[cc], vv[cc].x, o[i][0]);
                    o[i][1] = fmaf(pi[cc], vv[cc].y, o[i][1]);
                    o[i][2] = fmaf(pi[cc], vv[cc].z, o[i][2]);
                    o[i][3] = fmaf(pi[cc], vv[cc].w, o[i][3]);
                }
            }
        }
    }
    if (t < 64) rowl[t] = l_reg;
    __syncthreads();
    #pragma unroll
    for (int i = 0; i < 4; ++i) {
        int qrow = q0 + ty * 4 + i;
        if (qrow < SEQ) {
            float inv = 1.0f / rowl[ty * 4 + i];
            float* dst = out + (size_t)(b * SEQ + qrow) * CH + h * HD + tx * 4;
            dst[0] = o[i][0] * inv;
            dst[1] = o[i][1] * inv;
            dst[2] = o[i][2] * inv;
            dst[3] = o[i][3] * inv;
        }
    }
}

// ---------------- K3: output projection GEMM (M=9232, K=768, N=768) ----------------
__global__ __launch_bounds__(256) void out_gemm_k(
    const float* __restrict__ a, const float* __restrict__ w,
    const float* __restrict__ bias, float* __restrict__ out)
{
    __shared__ float As[16][68];
    __shared__ float Bs[16][68];
    const int t  = threadIdx.x;
    const int tx = t & 15, ty = t >> 4;
    const int m0 = blockIdx.y * 64;
    const int n0 = blockIdx.x * 64;
    float acc[4][4] = {};
    for (int k0 = 0; k0 < CH; k0 += 16) {
        #pragma unroll
        for (int i = 0; i < 4; ++i) {
            int idx = t + i * 256;
            int mm = idx >> 4, kk = idx & 15;
            int gm = m0 + mm;
            As[kk][mm] = (gm < MROWS) ? a[(size_t)gm * CH + k0 + kk] : 0.f;
        }
        #pragma unroll
        for (int i = 0; i < 4; ++i) {
            int idx = t + i * 256;
            int kk = idx >> 6, nn = idx & 63;
            Bs[kk][nn] = w[(size_t)(k0 + kk) * CH + n0 + nn];
        }
        __syncthreads();
        #pragma unroll
        for (int kk = 0; kk < 16; ++kk) {
            float4 av4 = *(const float4*)&As[kk][ty * 4];
            float4 bv4 = *(const float4*)&Bs[kk][tx * 4];
            float av[4] = {av4.x, av4.y, av4.z, av4.w};
            float bv[4] = {bv4.x, bv4.y, bv4.z, bv4.w};
            #pragma unroll
            for (int i = 0; i < 4; ++i)
                #pragma unroll
                for (int j = 0; j < 4; ++j)
                    acc[i][j] = fmaf(av[i], bv[j], acc[i][j]);
        }
        __syncthreads();
    }
    #pragma unroll
    for (int i = 0; i < 4; ++i) {
        int gm = m0 + ty * 4 + i;
        if (gm < MROWS) {
            #pragma unroll
            for (int j = 0; j < 4; ++j) {
                int nn = n0 + tx * 4 + j;
                out[(size_t)gm * CH + nn] = acc[i][j] + bias[nn];
            }
        }
    }
}

extern "C" void kernel_launch(void* const* d_in, const int* in_sizes, int n_in,
                              void* d_out, int out_size, void* d_ws, size_t ws_size,
                              hipStream_t stream) {
    const float* x        = (const float*)d_in[0];
    const float* qkv_w    = (const float*)d_in[1];
    const float* qkv_b    = (const float*)d_in[2];
    const float* pos_emb  = (const float*)d_in[3];
    const float* out_w    = (const float*)d_in[4];
    const float* out_b    = (const float*)d_in[5];
    const int*   rel_idx  = (const int*)d_in[6];
    float* out = (float*)d_out;
    float* ws  = (float*)d_ws;

    const size_t QS = (size_t)BATCH * NH * SEQ * HD;  // 7,090,176 floats
    float* qb   = ws;
    float* kb   = ws + QS;
    float* vb   = ws + 2 * QS;
    float* attn = ws + 3 * QS;   // (B,N,C) layout

    qkv_gemm_k<<<dim3(3 * CH / 64, (MROWS + 63) / 64), 256, 0, stream>>>(
        x, qkv_w, qkv_b, qb, kb, vb);
    attn_k<<<dim3((SEQ + 63) / 64, BATCH * NH), 256, 0, stream>>>(
        qb, kb, vb, pos_emb, rel_idx, attn);
    out_gemm_k<<<dim3(CH / 64, (MROWS + 63) / 64), 256, 0, stream>>>(
        attn, out_w, out_b, out);
}

// Round 2
// 619.678 us; speedup vs baseline: 1.8611x; 1.8611x over previous
//
#include <hip/hip_runtime.h>

// EnhanceSelfAttention  B=16, N=577, C=768, H=12, d=64.
// R2: bf16 MFMA for QKV and proj GEMMs (m97 128^2 template, global_load_lds w=16,
//     B^T weight layout via pre-transpose). Attention kernel unchanged fp32
//     (next round), but now writes bf16 output consumed by proj GEMM.

#define BATCH 16
#define SEQ   577
#define CH    768
#define NH    12
#define HD    64
#define MROWS (BATCH*SEQ)   // 9232
#define NRD   2212
#define SCALE 0.125f

#define BM 128
#define BN 128
#define BK 64

typedef __attribute__((ext_vector_type(8))) short bf16x8;
typedef __attribute__((ext_vector_type(4))) float f32x4;
typedef const __attribute__((address_space(1))) unsigned int* gp_t;
typedef __attribute__((address_space(3))) unsigned int* lp_t;

static __device__ __forceinline__ unsigned short f2bf(float f) {
    unsigned int u = __float_as_uint(f);
    u = (u + 0x7FFFu + ((u >> 16) & 1u)) >> 16;
    return (unsigned short)u;
}

// ---------- prep: fp32 -> bf16 straight copy (x) ----------
__global__ __launch_bounds__(256) void conv_bf16_k(
    const float* __restrict__ in, unsigned short* __restrict__ out, int n4)
{
    int i = blockIdx.x * 256 + threadIdx.x;
    if (i < n4) {
        float4 v = ((const float4*)in)[i];
        ushort4 o;
        o.x = f2bf(v.x); o.y = f2bf(v.y); o.z = f2bf(v.z); o.w = f2bf(v.w);
        ((ushort4*)out)[i] = o;
    }
}

// ---------- prep: fp32 (K,N) -> bf16 (N,K) transpose ----------
__global__ __launch_bounds__(256) void transpose_bf16_k(
    const float* __restrict__ w, unsigned short* __restrict__ wt, int K, int N)
{
    __shared__ float tile[32][33];
    const int n0 = blockIdx.x * 32, k0 = blockIdx.y * 32;
    const int tx = threadIdx.x & 31, ty = threadIdx.x >> 5;
    #pragma unroll
    for (int i = 0; i < 32; i += 8)
        tile[ty + i][tx] = w[(size_t)(k0 + ty + i) * N + n0 + tx];
    __syncthreads();
    #pragma unroll
    for (int i = 0; i < 32; i += 8)
        wt[(size_t)(n0 + ty + i) * K + k0 + tx] = f2bf(tile[tx][ty + i]);
}

// ---------- bf16 MFMA GEMM, A (M,K) bf16, Bt (N,K) bf16, fp32 out ----------
// MODE 0: QKV -> scatter q/k/v (B,H,N,d) fp32 + bias.  MODE 1: plain (M,N) + bias.
template<int MODE>
__global__ __launch_bounds__(256) void gemm_bf16_k(
    const unsigned short* __restrict__ A, const unsigned short* __restrict__ Bt,
    const float* __restrict__ bias, float* __restrict__ o0,
    float* __restrict__ o1, float* __restrict__ o2, int Kdim)
{
    __shared__ unsigned short Asm[BM * BK];
    __shared__ unsigned short Bsm[BN * BK];
    const int t = threadIdx.x;
    const int wid = t >> 6, lane = t & 63;
    const int m0 = blockIdx.y * BM;
    const int n0 = blockIdx.x * BN;
    const int wr = wid >> 1, wc = wid & 1;
    const int lr = lane & 15, lg = lane >> 4;

    f32x4 acc[4][4] = {};

    for (int k0 = 0; k0 < Kdim; k0 += BK) {
        __syncthreads();
        #pragma unroll
        for (int r = 0; r < 4; ++r) {
            int c = t + r * 256;
            int row = c >> 3, seg = c & 7;
            int gm = m0 + row; gm = gm < MROWS ? gm : MROWS - 1;
            __builtin_amdgcn_global_load_lds(
                (gp_t)(const void*)(A + (size_t)gm * Kdim + k0 + seg * 8),
                (lp_t)(void*)(Asm + c * 8), 16, 0, 0);
        }
        #pragma unroll
        for (int r = 0; r < 4; ++r) {
            int c = t + r * 256;
            int row = c >> 3, seg = c & 7;
            __builtin_amdgcn_global_load_lds(
                (gp_t)(const void*)(Bt + (size_t)(n0 + row) * Kdim + k0 + seg * 8),
                (lp_t)(void*)(Bsm + c * 8), 16, 0, 0);
        }
        __syncthreads();

        const unsigned short* Abase = Asm + (wr * 64 + lr) * BK + lg * 8;
        const unsigned short* Bbase = Bsm + (wc * 64 + lr) * BK + lg * 8;
        #pragma unroll
        for (int kh = 0; kh < 2; ++kh) {
            bf16x8 af[4], bfr[4];
            #pragma unroll
            for (int mi = 0; mi < 4; ++mi)
                af[mi] = *(const bf16x8*)(Abase + mi * 16 * BK + kh * 32);
            #pragma unroll
            for (int ni = 0; ni < 4; ++ni)
                bfr[ni] = *(const bf16x8*)(Bbase + ni * 16 * BK + kh * 32);
            #pragma unroll
            for (int mi = 0; mi < 4; ++mi)
                #pragma unroll
                for (int ni = 0; ni < 4; ++ni)
                    acc[mi][ni] = __builtin_amdgcn_mfma_f32_16x16x32_bf16(
                        af[mi], bfr[ni], acc[mi][ni], 0, 0, 0);
        }
    }

    #pragma unroll
    for (int ni = 0; ni < 4; ++ni) {
        const int gn = n0 + wc * 64 + ni * 16 + lr;
        const float bs = bias[gn];
        if (MODE == 0) {
            const int i3 = gn / CH;
            const int hh = (gn % CH) / HD;
            const int dd = gn % HD;
            float* dst = (i3 == 0) ? o0 : (i3 == 1) ? o1 : o2;
            #pragma unroll
            for (int mi = 0; mi < 4; ++mi) {
                #pragma unroll
                for (int j = 0; j < 4; ++j) {
                    int gm = m0 + wr * 64 + mi * 16 + lg * 4 + j;
                    if (gm < MROWS) {
                        int bb = gm / SEQ, ss = gm % SEQ;
                        dst[((size_t)(bb * NH + hh) * SEQ + ss) * HD + dd] =
                            acc[mi][ni][j] + bs;
                    }
                }
            }
        } else {
            #pragma unroll
            for (int mi = 0; mi < 4; ++mi) {
                #pragma unroll
                for (int j = 0; j < 4; ++j) {
                    int gm = m0 + wr * 64 + mi * 16 + lg * 4 + j;
                    if (gm < MROWS)
                        o0[(size_t)gm * CH + gn] = acc[mi][ni][j] + bs;
                }
            }
        }
    }
}

// ---------------- K2: flash attention (fp32, unchanged math; bf16 output) ----------------
__global__ __launch_bounds__(256) void attn_k(
    const float* __restrict__ qg, const float* __restrict__ kg, const float* __restrict__ vg,
    const float* __restrict__ pos_emb, const int* __restrict__ rel_index,
    unsigned short* __restrict__ out)
{
    __shared__ float Qs[64][68];
    __shared__ float KVs[64][68];
    __shared__ float Ss[64][68];
    __shared__ float pe[NRD];
    __shared__ float pmax[64][4];
    __shared__ float psum[64][4];
    __shared__ float rowm[64];
    __shared__ float rowf[64];
    __shared__ float rowl[64];

    const int qb = blockIdx.x;
    const int bh = blockIdx.y;
    const int b = bh / NH, h = bh % NH;
    const int t  = threadIdx.x;
    const int tx = t & 15, ty = t >> 4;
    const int q0 = qb * 64;

    const float* qbase = qg + (size_t)(b * NH + h) * SEQ * HD;
    const float* kbase = kg + (size_t)(b * NH + h) * SEQ * HD;
    const float* vbase = vg + (size_t)(b * NH + h) * SEQ * HD;

    for (int i = t; i < NRD; i += 256) pe[i] = pos_emb[(size_t)h * NRD + i];

    #pragma unroll
    for (int i = 0; i < 16; ++i) {
        int idx = t + i * 256;
        int r = idx >> 6, d = idx & 63;
        int row = q0 + r;
        Qs[r][d] = (row < SEQ) ? qbase[(size_t)row * HD + d] : 0.f;
    }

    float o[4][4] = {};
    float m_reg = -3.0e38f, l_reg = 0.f;

    for (int kb = 0; kb <= qb; ++kb) {
        const int k0 = kb * 64;
        __syncthreads();
        #pragma unroll
        for (int i = 0; i < 16; ++i) {
            int idx = t + i * 256;
            int r = idx >> 6, d = idx & 63;
            int row = k0 + r;
            KVs[r][d] = (row < SEQ) ? kbase[(size_t)row * HD + d] : 0.f;
        }
        __syncthreads();
        float s[4][4] = {};
        #pragma unroll 4
        for (int d4 = 0; d4 < 64; d4 += 4) {
            float4 a[4], bb[4];
            #pragma unroll
            for (int i = 0; i < 4; ++i) a[i]  = *(const float4*)&Qs[ty * 4 + i][d4];
            #pragma unroll
            for (int j = 0; j < 4; ++j) bb[j] = *(const float4*)&KVs[tx * 4 + j][d4];
            #pragma unroll
            for (int i = 0; i < 4; ++i) {
                #pragma unroll
                for (int j = 0; j < 4; ++j) {
                    s[i][j] = fmaf(a[i].x, bb[j].x, s[i][j]);
                    s[i][j] = fmaf(a[i].y, bb[j].y, s[i][j]);
                    s[i][j] = fmaf(a[i].z, bb[j].z, s[i][j]);
                    s[i][j] = fmaf(a[i].w, bb[j].w, s[i][j]);
                }
            }
        }
        #pragma unroll
        for (int i = 0; i < 4; ++i) {
            int qrow = q0 + ty * 4 + i;
            #pragma unroll
            for (int j = 0; j < 4; ++j) {
                int kcol = k0 + tx * 4 + j;
                float val;
                if (qrow < SEQ && kcol < SEQ && kcol <= qrow) {
                    int ridx = rel_index[(size_t)qrow * SEQ + kcol];
                    val = s[i][j] * SCALE + pe[ridx];
                } else {
                    val = -65504.f;
                }
                Ss[ty * 4 + i][tx * 4 + j] = val;
            }
        }
        __syncthreads();
        #pragma unroll
        for (int i = 0; i < 16; ++i) {
            int idx = t + i * 256;
            int r = idx >> 6, d = idx & 63;
            int row = k0 + r;
            KVs[r][d] = (row < SEQ) ? vbase[(size_t)row * HD + d] : 0.f;
        }
        {
            int row = t & 63, seg = t >> 6;
            float pm = -3.0e38f;
            #pragma unroll
            for (int c4 = 0; c4 < 4; ++c4) {
                float4 v4 = *(const float4*)&Ss[row][seg * 16 + c4 * 4];
                pm = fmaxf(pm, fmaxf(fmaxf(v4.x, v4.y), fmaxf(v4.z, v4.w)));
            }
            pmax[row][seg] = pm;
        }
        __syncthreads();
        if (t < 64) {
            float bm = fmaxf(fmaxf(pmax[t][0], pmax[t][1]), fmaxf(pmax[t][2], pmax[t][3]));
            float mn = fmaxf(m_reg, bm);
            float f  = __expf(m_reg - mn);
            m_reg = mn;
            l_reg *= f;
            rowm[t] = mn;
            rowf[t] = f;
        }
        __syncthreads();
        {
            int row = t & 63, seg = t >> 6;
            float mn = rowm[row];
            float sum = 0.f;
            #pragma unroll
            for (int c4 = 0; c4 < 4; ++c4) {
                float4 v4 = *(const float4*)&Ss[row][seg * 16 + c4 * 4];
                v4.x = __expf(v4.x - mn); v4.y = __expf(v4.y - mn);
                v4.z = __expf(v4.z - mn); v4.w = __expf(v4.w - mn);
                *(float4*)&Ss[row][seg * 16 + c4 * 4] = v4;
                sum += v4.x + v4.y + v4.z + v4.w;
            }
            psum[row][seg] = sum;
        }
        __syncthreads();
        if (t < 64) {
            l_reg += psum[t][0] + psum[t][1] + psum[t][2] + psum[t][3];
        }
        float fr[4];
        #pragma unroll
        for (int i = 0; i < 4; ++i) fr[i] = rowf[ty * 4 + i];
        #pragma unroll
        for (int i = 0; i < 4; ++i)
            #pragma unroll
            for (int j = 0; j < 4; ++j) o[i][j] *= fr[i];
        #pragma unroll 4
        for (int c4 = 0; c4 < 64; c4 += 4) {
            float4 p[4], vv[4];
            #pragma unroll
            for (int i = 0; i < 4; ++i)  p[i]  = *(const float4*)&Ss[ty * 4 + i][c4];
            #pragma unroll
            for (int cc = 0; cc < 4; ++cc) vv[cc] = *(const float4*)&KVs[c4 + cc][tx * 4];
            #pragma unroll
            for (int i = 0; i < 4; ++i) {
                float pi[4] = {p[i].x, p[i].y, p[i].z, p[i].w};
                #pragma unroll
                for (int cc = 0; cc < 4; ++cc) {
                    o[i][0] = fmaf(pi[cc], vv[cc].x, o[i][0]);
                    o[i][1] = fmaf(pi[cc], vv[cc].y, o[i][1]);
                    o[i][2] = fmaf(pi[cc], vv[cc].z, o[i][2]);
                    o[i][3] = fmaf(pi[cc], vv[cc].w, o[i][3]);
                }
            }
        }
    }
    if (t < 64) rowl[t] = l_reg;
    __syncthreads();
    #pragma unroll
    for (int i = 0; i < 4; ++i) {
        int qrow = q0 + ty * 4 + i;
        if (qrow < SEQ) {
            float inv = 1.0f / rowl[ty * 4 + i];
            unsigned short* dst = out + (size_t)(b * SEQ + qrow) * CH + h * HD + tx * 4;
            ushort4 o4;
            o4.x = f2bf(o[i][0] * inv);
            o4.y = f2bf(o[i][1] * inv);
            o4.z = f2bf(o[i][2] * inv);
            o4.w = f2bf(o[i][3] * inv);
            *(ushort4*)dst = o4;
        }
    }
}

extern "C" void kernel_launch(void* const* d_in, const int* in_sizes, int n_in,
                              void* d_out, int out_size, void* d_ws, size_t ws_size,
                              hipStream_t stream) {
    const float* x        = (const float*)d_in[0];
    const float* qkv_w    = (const float*)d_in[1];
    const float* qkv_b    = (const float*)d_in[2];
    const float* pos_emb  = (const float*)d_in[3];
    const float* out_w    = (const float*)d_in[4];
    const float* out_b    = (const float*)d_in[5];
    const int*   rel_idx  = (const int*)d_in[6];
    float* out = (float*)d_out;
    char*  ws  = (char*)d_ws;

    const size_t QS = (size_t)BATCH * NH * SEQ * HD;       // 7,090,176
    float* qf = (float*)ws;                                // QS f32
    float* kf = qf + QS;
    float* vf = kf + QS;
    unsigned short* xb  = (unsigned short*)(vf + QS);      // 9232*768 bf16 (aliases attn-out)
    unsigned short* qwt = xb + (size_t)MROWS * CH;         // 2304*768 bf16 (qkv_w^T)
    unsigned short* owt = qwt + (size_t)(3 * CH) * CH;     // 768*768 bf16 (out_w^T)

    // prep
    conv_bf16_k<<<(MROWS * CH / 4 + 255) / 256, 256, 0, stream>>>(x, xb, MROWS * CH / 4);
    transpose_bf16_k<<<dim3(3 * CH / 32, CH / 32), 256, 0, stream>>>(qkv_w, qwt, CH, 3 * CH);
    transpose_bf16_k<<<dim3(CH / 32, CH / 32), 256, 0, stream>>>(out_w, owt, CH, CH);

    // K1: qkv
    gemm_bf16_k<0><<<dim3(3 * CH / BN, (MROWS + BM - 1) / BM), 256, 0, stream>>>(
        xb, qwt, qkv_b, qf, kf, vf, CH);

    // K2: attention (writes bf16 into xb — x_bf16 dead after K1)
    attn_k<<<dim3((SEQ + 63) / 64, BATCH * NH), 256, 0, stream>>>(
        qf, kf, vf, pos_emb, rel_idx, xb);

    // K3: projection
    gemm_bf16_k<1><<<dim3(CH / BN, (MROWS + BM - 1) / BM), 256, 0, stream>>>(
        xb, owt, out_b, out, nullptr, nullptr, CH);
}

// Round 4
// 212.084 us; speedup vs baseline: 5.4378x; 2.9218x over previous
//
#include <hip/hip_runtime.h>

// EnhanceSelfAttention  B=16, N=577, C=768, H=12, d=64.
// R4: same as R3 with the K3 launch-arg compile fix (8 args).
//     Full bf16-MFMA pipeline: QKV GEMM -> bf16 q/k/v (padded, q pre-scaled),
//     V^T transpose, precomputed rel-pos bias table, MFMA flash attention with
//     in-register wave-parallel online softmax + XOR-swizzled LDS, proj GEMM.

#define BATCH 16
#define SEQ   577
#define CH    768
#define NH    12
#define HD    64
#define MROWS (BATCH*SEQ)   // 9232
#define NRD   2212
#define NP    640           // padded seq (10 x 64)

#define BM 128
#define BN 128
#define BK 64

typedef __attribute__((ext_vector_type(8))) short bf16x8;
typedef __attribute__((ext_vector_type(4))) float f32x4;
typedef const __attribute__((address_space(1))) unsigned int* gp_t;
typedef __attribute__((address_space(3))) unsigned int* lp_t;

static __device__ __forceinline__ unsigned short f2bf(float f) {
    unsigned int u = __float_as_uint(f);
    u = (u + 0x7FFFu + ((u >> 16) & 1u)) >> 16;
    return (unsigned short)u;
}
static __device__ __forceinline__ float bf2f(unsigned short b) {
    return __uint_as_float(((unsigned int)b) << 16);
}

// ---------- prep: fp32 -> bf16 straight copy (x) ----------
__global__ __launch_bounds__(256) void conv_bf16_k(
    const float* __restrict__ in, unsigned short* __restrict__ out, int n4)
{
    int i = blockIdx.x * 256 + threadIdx.x;
    if (i < n4) {
        float4 v = ((const float4*)in)[i];
        ushort4 o;
        o.x = f2bf(v.x); o.y = f2bf(v.y); o.z = f2bf(v.z); o.w = f2bf(v.w);
        ((ushort4*)out)[i] = o;
    }
}

// ---------- prep: fp32 (K,N) -> bf16 (N,K) transpose ----------
__global__ __launch_bounds__(256) void transpose_bf16_k(
    const float* __restrict__ w, unsigned short* __restrict__ wt, int K, int N)
{
    __shared__ float tile[32][33];
    const int n0 = blockIdx.x * 32, k0 = blockIdx.y * 32;
    const int tx = threadIdx.x & 31, ty = threadIdx.x >> 5;
    #pragma unroll
    for (int i = 0; i < 32; i += 8)
        tile[ty + i][tx] = w[(size_t)(k0 + ty + i) * N + n0 + tx];
    __syncthreads();
    #pragma unroll
    for (int i = 0; i < 32; i += 8)
        wt[(size_t)(n0 + ty + i) * K + k0 + tx] = f2bf(tile[tx][ty + i]);
}

// ---------- prep: bias_bf16[h][q][k] = pos_emb[h, rel_index[q,k]] ----------
__global__ __launch_bounds__(256) void bias_k(
    const float* __restrict__ pos_emb, const int* __restrict__ rel_index,
    unsigned short* __restrict__ biasg)
{
    int i = blockIdx.x * 256 + threadIdx.x;
    if (i < SEQ * SEQ) {
        int idx = rel_index[i];
        #pragma unroll
        for (int h = 0; h < NH; ++h)
            biasg[(size_t)h * SEQ * SEQ + i] = f2bf(pos_emb[h * NRD + idx]);
    }
}

// ---------- prep: v (bh, NP, 64) -> vt (bh, 64, NP) ----------
__global__ __launch_bounds__(256) void vtrans_k(
    const unsigned short* __restrict__ v, unsigned short* __restrict__ vt)
{
    __shared__ unsigned short tile[64][68];
    const int bh = blockIdx.y;
    const int n0 = blockIdx.x * 64;
    const int tx = threadIdx.x & 7;   // 8 cols of 8
    const int ty = threadIdx.x >> 3;  // 32 rows
    const unsigned short* src = v + ((size_t)bh * NP + n0) * HD;
    #pragma unroll
    for (int i = 0; i < 2; ++i) {
        int r = ty + i * 32;
        *(bf16x8*)&tile[r][tx * 8] = *(const bf16x8*)(src + (size_t)r * HD + tx * 8);
    }
    __syncthreads();
    unsigned short* dst = vt + (size_t)bh * HD * NP + n0;
    #pragma unroll
    for (int i = 0; i < 2; ++i) {
        int d = ty + i * 32;
        bf16x8 o;
        #pragma unroll
        for (int e = 0; e < 8; ++e) o[e] = (short)tile[tx * 8 + e][d];
        *(bf16x8*)(dst + (size_t)d * NP + tx * 8) = o;
    }
}

// ---------- bf16 MFMA GEMM ----------
// MODE 0: QKV -> bf16 q/k/v scatter, padded (bh, NP, 64), q pre-scaled 0.125.
// MODE 1: plain fp32 (M,N) + bias.
template<int MODE>
__global__ __launch_bounds__(256) void gemm_bf16_k(
    const unsigned short* __restrict__ A, const unsigned short* __restrict__ Bt,
    const float* __restrict__ bias, float* __restrict__ fo,
    unsigned short* __restrict__ qo, unsigned short* __restrict__ ko,
    unsigned short* __restrict__ vo, int Kdim)
{
    __shared__ unsigned short Asm[BM * BK];
    __shared__ unsigned short Bsm[BN * BK];
    const int t = threadIdx.x;
    const int wid = t >> 6, lane = t & 63;
    const int m0 = blockIdx.y * BM;
    const int n0 = blockIdx.x * BN;
    const int wr = wid >> 1, wc = wid & 1;
    const int lr = lane & 15, lg = lane >> 4;

    f32x4 acc[4][4] = {};

    for (int k0 = 0; k0 < Kdim; k0 += BK) {
        __syncthreads();
        #pragma unroll
        for (int r = 0; r < 4; ++r) {
            int c = t + r * 256;
            int row = c >> 3, seg = c & 7;
            int gm = m0 + row; gm = gm < MROWS ? gm : MROWS - 1;
            __builtin_amdgcn_global_load_lds(
                (gp_t)(const void*)(A + (size_t)gm * Kdim + k0 + seg * 8),
                (lp_t)(void*)(Asm + c * 8), 16, 0, 0);
        }
        #pragma unroll
        for (int r = 0; r < 4; ++r) {
            int c = t + r * 256;
            int row = c >> 3, seg = c & 7;
            __builtin_amdgcn_global_load_lds(
                (gp_t)(const void*)(Bt + (size_t)(n0 + row) * Kdim + k0 + seg * 8),
                (lp_t)(void*)(Bsm + c * 8), 16, 0, 0);
        }
        __syncthreads();

        const unsigned short* Abase = Asm + (wr * 64 + lr) * BK + lg * 8;
        const unsigned short* Bbase = Bsm + (wc * 64 + lr) * BK + lg * 8;
        #pragma unroll
        for (int kh = 0; kh < 2; ++kh) {
            bf16x8 af[4], bfr[4];
            #pragma unroll
            for (int mi = 0; mi < 4; ++mi)
                af[mi] = *(const bf16x8*)(Abase + mi * 16 * BK + kh * 32);
            #pragma unroll
            for (int ni = 0; ni < 4; ++ni)
                bfr[ni] = *(const bf16x8*)(Bbase + ni * 16 * BK + kh * 32);
            #pragma unroll
            for (int mi = 0; mi < 4; ++mi)
                #pragma unroll
                for (int ni = 0; ni < 4; ++ni)
                    acc[mi][ni] = __builtin_amdgcn_mfma_f32_16x16x32_bf16(
                        af[mi], bfr[ni], acc[mi][ni], 0, 0, 0);
        }
    }

    #pragma unroll
    for (int ni = 0; ni < 4; ++ni) {
        const int gn = n0 + wc * 64 + ni * 16 + lr;
        const float bs = bias[gn];
        if (MODE == 0) {
            const int i3 = gn / CH;
            const int hh = (gn % CH) / HD;
            const int dd = gn % HD;
            unsigned short* dst = (i3 == 0) ? qo : (i3 == 1) ? ko : vo;
            const float scl = (i3 == 0) ? 0.125f : 1.0f;
            #pragma unroll
            for (int mi = 0; mi < 4; ++mi) {
                #pragma unroll
                for (int j = 0; j < 4; ++j) {
                    int gm = m0 + wr * 64 + mi * 16 + lg * 4 + j;
                    if (gm < MROWS) {
                        int bb = gm / SEQ, ss = gm % SEQ;
                        dst[((size_t)(bb * NH + hh) * NP + ss) * HD + dd] =
                            f2bf((acc[mi][ni][j] + bs) * scl);
                    }
                }
            }
        } else {
            #pragma unroll
            for (int mi = 0; mi < 4; ++mi) {
                #pragma unroll
                for (int j = 0; j < 4; ++j) {
                    int gm = m0 + wr * 64 + mi * 16 + lg * 4 + j;
                    if (gm < MROWS)
                        fo[(size_t)gm * CH + gn] = acc[mi][ni][j] + bs;
                }
            }
        }
    }
}

// ---------------- MFMA flash attention ----------------
// grid (10, 192): x -> q-block (reversed: longest first), y -> b*H+h.
// 4 waves, each owns 16 q-rows of the 64-row q-tile. S tile 64x64 per k-tile.
__global__ __launch_bounds__(256) void attn_mfma_k(
    const unsigned short* __restrict__ qg,   // (192, NP, 64) bf16, pre-scaled
    const unsigned short* __restrict__ kg,   // (192, NP, 64) bf16
    const unsigned short* __restrict__ vtg,  // (192, 64, NP) bf16
    const unsigned short* __restrict__ biasg,// (12, 577, 577) bf16
    unsigned short* __restrict__ out)        // (B*SEQ, CH) bf16
{
    __shared__ unsigned short Qs[64 * 64];
    __shared__ unsigned short Ks[64 * 64];
    __shared__ unsigned short VTs[64 * 64];
    __shared__ unsigned short Ps[64 * 64];

    const int qb = 9 - blockIdx.x;
    const int bh = blockIdx.y;
    const int b = bh / NH, h = bh % NH;
    const int t = threadIdx.x;
    const int wid = t >> 6;
    const int lane = t & 63;
    const int lr = lane & 15, lg = lane >> 4;
    const int q0 = qb * 64;

    const size_t kvbase = (size_t)bh * NP * HD;
    const size_t vtbase = (size_t)bh * HD * NP;

    // stage Q (pre-swizzled global source -> linear LDS; swizzle g^=(row&7))
    #pragma unroll
    for (int r = 0; r < 2; ++r) {
        int c = t + r * 256;
        int row = c >> 3, gsrc = (c & 7) ^ (row & 7);
        __builtin_amdgcn_global_load_lds(
            (gp_t)(const void*)(qg + kvbase + (size_t)(q0 + row) * HD + gsrc * 8),
            (lp_t)(void*)(Qs + c * 8), 16, 0, 0);
    }

    f32x4 o_acc[4] = {};
    float m_j[4], l_j[4];
    #pragma unroll
    for (int j = 0; j < 4; ++j) { m_j[j] = -3.0e38f; l_j[j] = 0.f; }

    const int qrow0 = q0 + wid * 16 + lg * 4;

    for (int kb = 0; kb <= qb; ++kb) {
        const int k0 = kb * 64;
        __syncthreads();   // prev tile fully consumed (incl. Q on first pass)
        #pragma unroll
        for (int r = 0; r < 2; ++r) {
            int c = t + r * 256;
            int row = c >> 3, gsrc = (c & 7) ^ (row & 7);
            __builtin_amdgcn_global_load_lds(
                (gp_t)(const void*)(kg + kvbase + (size_t)(k0 + row) * HD + gsrc * 8),
                (lp_t)(void*)(Ks + c * 8), 16, 0, 0);
        }
        #pragma unroll
        for (int r = 0; r < 2; ++r) {
            int c = t + r * 256;
            int row = c >> 3, gsrc = (c & 7) ^ (row & 7);
            __builtin_amdgcn_global_load_lds(
                (gp_t)(const void*)(vtg + vtbase + (size_t)row * NP + k0 + gsrc * 8),
                (lp_t)(void*)(VTs + c * 8), 16, 0, 0);
        }
        __syncthreads();   // tiles landed

        // ---- S = Q K^T (per wave: 16 q-rows x 64 k-cols) ----
        f32x4 s_acc[4] = {};
        #pragma unroll
        for (int kh = 0; kh < 2; ++kh) {
            const int arow = wid * 16 + lr;
            bf16x8 aq = *(const bf16x8*)(Qs + arow * 64 + ((((kh << 2) | lg)) ^ (arow & 7)) * 8);
            #pragma unroll
            for (int ni = 0; ni < 4; ++ni) {
                const int brow = ni * 16 + lr;
                bf16x8 bk = *(const bf16x8*)(Ks + brow * 64 + ((((kh << 2) | lg)) ^ (brow & 7)) * 8);
                s_acc[ni] = __builtin_amdgcn_mfma_f32_16x16x32_bf16(aq, bk, s_acc[ni], 0, 0, 0);
            }
        }

        // ---- bias + causal mask + online softmax (in-register, butterfly over lr) ----
        float pv[4][4];   // [ni][j]
        #pragma unroll
        for (int j = 0; j < 4; ++j) {
            const int qrow = qrow0 + j;
            const int qc = qrow < SEQ ? qrow : SEQ - 1;
            float mx = -3.0e38f;
            #pragma unroll
            for (int ni = 0; ni < 4; ++ni) {
                const int kcol = k0 + ni * 16 + lr;
                const int kc = kcol < SEQ ? kcol : SEQ - 1;
                float v = s_acc[ni][j] + bf2f(biasg[((size_t)h * SEQ + qc) * SEQ + kc]);
                if (kcol > qrow) v = -65504.f;
                pv[ni][j] = v;
                mx = fmaxf(mx, v);
            }
            #pragma unroll
            for (int off = 1; off < 16; off <<= 1)
                mx = fmaxf(mx, __shfl_xor(mx, off, 64));
            const float mnew = fmaxf(m_j[j], mx);
            const float f = __expf(m_j[j] - mnew);
            m_j[j] = mnew;
            float sum = 0.f;
            #pragma unroll
            for (int ni = 0; ni < 4; ++ni) {
                float p = __expf(pv[ni][j] - mnew);
                pv[ni][j] = p;
                sum += p;
            }
            #pragma unroll
            for (int off = 1; off < 16; off <<= 1)
                sum += __shfl_xor(sum, off, 64);
            l_j[j] = l_j[j] * f + sum;
            #pragma unroll
            for (int ni = 0; ni < 4; ++ni) o_acc[ni][j] *= f;
        }

        // ---- P -> bf16 -> swizzled LDS ----
        #pragma unroll
        for (int j = 0; j < 4; ++j) {
            const int prow = wid * 16 + lg * 4 + j;
            #pragma unroll
            for (int ni = 0; ni < 4; ++ni) {
                const int col = ni * 16 + lr;
                Ps[prow * 64 + (((col >> 3) ^ (prow & 7)) << 3) + (col & 7)] = f2bf(pv[ni][j]);
            }
        }
        __syncthreads();   // Ps visible

        // ---- O += P V (A from Ps, B from VTs) ----
        #pragma unroll
        for (int kh = 0; kh < 2; ++kh) {
            const int arow = wid * 16 + lr;
            bf16x8 pa = *(const bf16x8*)(Ps + arow * 64 + ((((kh << 2) | lg)) ^ (arow & 7)) * 8);
            #pragma unroll
            for (int ni = 0; ni < 4; ++ni) {
                const int brow = ni * 16 + lr;
                bf16x8 bv = *(const bf16x8*)(VTs + brow * 64 + ((((kh << 2) | lg)) ^ (brow & 7)) * 8);
                o_acc[ni] = __builtin_amdgcn_mfma_f32_16x16x32_bf16(pa, bv, o_acc[ni], 0, 0, 0);
            }
        }
    }

    // ---- epilogue: O / l -> out (bf16, (B*SEQ, CH)) ----
    #pragma unroll
    for (int j = 0; j < 4; ++j) {
        const int qrow = qrow0 + j;
        if (qrow < SEQ) {
            const float inv = 1.0f / l_j[j];
            const size_t base = ((size_t)b * SEQ + qrow) * CH + h * HD;
            #pragma unroll
            for (int ni = 0; ni < 4; ++ni)
                out[base + ni * 16 + lr] = f2bf(o_acc[ni][j] * inv);
        }
    }
}

extern "C" void kernel_launch(void* const* d_in, const int* in_sizes, int n_in,
                              void* d_out, int out_size, void* d_ws, size_t ws_size,
                              hipStream_t stream) {
    const float* x        = (const float*)d_in[0];
    const float* qkv_w    = (const float*)d_in[1];
    const float* qkv_b    = (const float*)d_in[2];
    const float* pos_emb  = (const float*)d_in[3];
    const float* out_w    = (const float*)d_in[4];
    const float* out_b    = (const float*)d_in[5];
    const int*   rel_idx  = (const int*)d_in[6];
    float* out = (float*)d_out;

    const size_t QP = (size_t)BATCH * NH * NP * HD;   // 7,864,320 elems (padded)
    unsigned short* qp  = (unsigned short*)d_ws;
    unsigned short* kp  = qp + QP;
    unsigned short* vp  = kp + QP;
    unsigned short* vt  = vp + QP;
    unsigned short* xb  = vt + QP;                        // x bf16; attn out aliases
    unsigned short* qwt = xb + (size_t)MROWS * CH;
    unsigned short* owt = qwt + (size_t)(3 * CH) * CH;
    unsigned short* bg  = owt + (size_t)CH * CH;          // bias table

    // prep
    conv_bf16_k<<<(MROWS * CH / 4 + 255) / 256, 256, 0, stream>>>(x, xb, MROWS * CH / 4);
    transpose_bf16_k<<<dim3(3 * CH / 32, CH / 32), 256, 0, stream>>>(qkv_w, qwt, CH, 3 * CH);
    transpose_bf16_k<<<dim3(CH / 32, CH / 32), 256, 0, stream>>>(out_w, owt, CH, CH);
    bias_k<<<(SEQ * SEQ + 255) / 256, 256, 0, stream>>>(pos_emb, rel_idx, bg);
    hipMemsetAsync(qp, 0, 3 * QP * sizeof(unsigned short), stream);  // zero pad rows

    // K1: qkv (bf16 outputs, padded, q scaled)
    gemm_bf16_k<0><<<dim3(3 * CH / BN, (MROWS + BM - 1) / BM), 256, 0, stream>>>(
        xb, qwt, qkv_b, nullptr, qp, kp, vp, CH);

    // V^T
    vtrans_k<<<dim3(NP / 64, BATCH * NH), 256, 0, stream>>>(vp, vt);

    // K2: attention (bf16 out into xb)
    attn_mfma_k<<<dim3(10, BATCH * NH), 256, 0, stream>>>(qp, kp, vt, bg, xb);

    // K3: projection
    gemm_bf16_k<1><<<dim3(CH / BN, (MROWS + BM - 1) / BM), 256, 0, stream>>>(
        xb, owt, out_b, out, nullptr, nullptr, nullptr, CH);
}

// Round 5
// 191.466 us; speedup vs baseline: 6.0234x; 1.1077x over previous
//
#include <hip/hip_runtime.h>

// EnhanceSelfAttention  B=16, N=577, C=768, H=12, d=64.
// R5: + T2 XOR-swizzle on GEMM LDS tiles (conflicts were 1.2e7), hoisted
//     epilogue divisions, dropped pad-memset (masked/zero-weighted pads).

#define BATCH 16
#define SEQ   577
#define CH    768
#define NH    12
#define HD    64
#define MROWS (BATCH*SEQ)   // 9232
#define NRD   2212
#define NP    640           // padded seq (10 x 64)

#define BM 128
#define BN 128
#define BK 64

typedef __attribute__((ext_vector_type(8))) short bf16x8;
typedef __attribute__((ext_vector_type(4))) float f32x4;
typedef const __attribute__((address_space(1))) unsigned int* gp_t;
typedef __attribute__((address_space(3))) unsigned int* lp_t;

static __device__ __forceinline__ unsigned short f2bf(float f) {
    unsigned int u = __float_as_uint(f);
    u = (u + 0x7FFFu + ((u >> 16) & 1u)) >> 16;
    return (unsigned short)u;
}
static __device__ __forceinline__ float bf2f(unsigned short b) {
    return __uint_as_float(((unsigned int)b) << 16);
}

// ---------- prep: fp32 -> bf16 straight copy (x) ----------
__global__ __launch_bounds__(256) void conv_bf16_k(
    const float* __restrict__ in, unsigned short* __restrict__ out, int n4)
{
    int i = blockIdx.x * 256 + threadIdx.x;
    if (i < n4) {
        float4 v = ((const float4*)in)[i];
        ushort4 o;
        o.x = f2bf(v.x); o.y = f2bf(v.y); o.z = f2bf(v.z); o.w = f2bf(v.w);
        ((ushort4*)out)[i] = o;
    }
}

// ---------- prep: fp32 (K,N) -> bf16 (N,K) transpose ----------
__global__ __launch_bounds__(256) void transpose_bf16_k(
    const float* __restrict__ w, unsigned short* __restrict__ wt, int K, int N)
{
    __shared__ float tile[32][33];
    const int n0 = blockIdx.x * 32, k0 = blockIdx.y * 32;
    const int tx = threadIdx.x & 31, ty = threadIdx.x >> 5;
    #pragma unroll
    for (int i = 0; i < 32; i += 8)
        tile[ty + i][tx] = w[(size_t)(k0 + ty + i) * N + n0 + tx];
    __syncthreads();
    #pragma unroll
    for (int i = 0; i < 32; i += 8)
        wt[(size_t)(n0 + ty + i) * K + k0 + tx] = f2bf(tile[tx][ty + i]);
}

// ---------- prep: bias_bf16[h][q][k] = pos_emb[h, rel_index[q,k]] ----------
__global__ __launch_bounds__(256) void bias_k(
    const float* __restrict__ pos_emb, const int* __restrict__ rel_index,
    unsigned short* __restrict__ biasg)
{
    int i = blockIdx.x * 256 + threadIdx.x;
    if (i < SEQ * SEQ) {
        int idx = rel_index[i];
        #pragma unroll
        for (int h = 0; h < NH; ++h)
            biasg[(size_t)h * SEQ * SEQ + i] = f2bf(pos_emb[h * NRD + idx]);
    }
}

// ---------- prep: v (bh, NP, 64) -> vt (bh, 64, NP) ----------
__global__ __launch_bounds__(256) void vtrans_k(
    const unsigned short* __restrict__ v, unsigned short* __restrict__ vt)
{
    __shared__ unsigned short tile[64][68];
    const int bh = blockIdx.y;
    const int n0 = blockIdx.x * 64;
    const int tx = threadIdx.x & 7;   // 8 cols of 8
    const int ty = threadIdx.x >> 3;  // 32 rows
    const unsigned short* src = v + ((size_t)bh * NP + n0) * HD;
    #pragma unroll
    for (int i = 0; i < 2; ++i) {
        int r = ty + i * 32;
        *(bf16x8*)&tile[r][tx * 8] = *(const bf16x8*)(src + (size_t)r * HD + tx * 8);
    }
    __syncthreads();
    unsigned short* dst = vt + (size_t)bh * HD * NP + n0;
    #pragma unroll
    for (int i = 0; i < 2; ++i) {
        int d = ty + i * 32;
        bf16x8 o;
        #pragma unroll
        for (int e = 0; e < 8; ++e) o[e] = (short)tile[tx * 8 + e][d];
        *(bf16x8*)(dst + (size_t)d * NP + tx * 8) = o;
    }
}

// ---------- bf16 MFMA GEMM (T2-swizzled LDS) ----------
// MODE 0: QKV -> bf16 q/k/v scatter, padded (bh, NP, 64), q pre-scaled 0.125.
// MODE 1: plain fp32 (M,N) + bias.
template<int MODE>
__global__ __launch_bounds__(256) void gemm_bf16_k(
    const unsigned short* __restrict__ A, const unsigned short* __restrict__ Bt,
    const float* __restrict__ bias, float* __restrict__ fo,
    unsigned short* __restrict__ qo, unsigned short* __restrict__ ko,
    unsigned short* __restrict__ vo, int Kdim)
{
    __shared__ unsigned short Asm[BM * BK];
    __shared__ unsigned short Bsm[BN * BK];
    const int t = threadIdx.x;
    const int wid = t >> 6, lane = t & 63;
    const int m0 = blockIdx.y * BM;
    const int n0 = blockIdx.x * BN;
    const int wr = wid >> 1, wc = wid & 1;
    const int lr = lane & 15, lg = lane >> 4;
    const int swz = lr & 7;

    f32x4 acc[4][4] = {};

    for (int k0 = 0; k0 < Kdim; k0 += BK) {
        __syncthreads();
        #pragma unroll
        for (int r = 0; r < 4; ++r) {
            int c = t + r * 256;
            int row = c >> 3, seg = (c & 7) ^ (row & 7);   // pre-swizzled source
            int gm = m0 + row; gm = gm < MROWS ? gm : MROWS - 1;
            __builtin_amdgcn_global_load_lds(
                (gp_t)(const void*)(A + (size_t)gm * Kdim + k0 + seg * 8),
                (lp_t)(void*)(Asm + c * 8), 16, 0, 0);
        }
        #pragma unroll
        for (int r = 0; r < 4; ++r) {
            int c = t + r * 256;
            int row = c >> 3, seg = (c & 7) ^ (row & 7);
            __builtin_amdgcn_global_load_lds(
                (gp_t)(const void*)(Bt + (size_t)(n0 + row) * Kdim + k0 + seg * 8),
                (lp_t)(void*)(Bsm + c * 8), 16, 0, 0);
        }
        __syncthreads();

        const unsigned short* Arow0 = Asm + (wr * 64 + lr) * BK;
        const unsigned short* Brow0 = Bsm + (wc * 64 + lr) * BK;
        #pragma unroll
        for (int kh = 0; kh < 2; ++kh) {
            const int goff = (((kh << 2) | lg) ^ swz) * 8;   // swizzled granule
            bf16x8 af[4], bfr[4];
            #pragma unroll
            for (int mi = 0; mi < 4; ++mi)
                af[mi] = *(const bf16x8*)(Arow0 + mi * 16 * BK + goff);
            #pragma unroll
            for (int ni = 0; ni < 4; ++ni)
                bfr[ni] = *(const bf16x8*)(Brow0 + ni * 16 * BK + goff);
            #pragma unroll
            for (int mi = 0; mi < 4; ++mi)
                #pragma unroll
                for (int ni = 0; ni < 4; ++ni)
                    acc[mi][ni] = __builtin_amdgcn_mfma_f32_16x16x32_bf16(
                        af[mi], bfr[ni], acc[mi][ni], 0, 0, 0);
        }
    }

    if (MODE == 0) {
        // hoisted row decomposition (independent of ni)
        int rbase[16];
        #pragma unroll
        for (int mi = 0; mi < 4; ++mi) {
            #pragma unroll
            for (int j = 0; j < 4; ++j) {
                int gm = m0 + wr * 64 + mi * 16 + lg * 4 + j;
                int bb = gm / SEQ, ss = gm - bb * SEQ;
                rbase[mi * 4 + j] = (gm < MROWS) ? (bb * NH * NP + ss) : -1;
            }
        }
        #pragma unroll
        for (int ni = 0; ni < 4; ++ni) {
            const int gn = n0 + wc * 64 + ni * 16 + lr;
            const float bs = bias[gn];
            const int i3 = gn / CH;
            const int hh = (gn % CH) / HD;
            const int dd = gn % HD;
            unsigned short* dst = (i3 == 0) ? qo : (i3 == 1) ? ko : vo;
            const float scl = (i3 == 0) ? 0.125f : 1.0f;
            #pragma unroll
            for (int mi = 0; mi < 4; ++mi) {
                #pragma unroll
                for (int j = 0; j < 4; ++j) {
                    int rb = rbase[mi * 4 + j];
                    if (rb >= 0)
                        dst[((size_t)rb + (size_t)hh * NP) * HD + dd] =
                            f2bf((acc[mi][ni][j] + bs) * scl);
                }
            }
        }
    } else {
        #pragma unroll
        for (int ni = 0; ni < 4; ++ni) {
            const int gn = n0 + wc * 64 + ni * 16 + lr;
            const float bs = bias[gn];
            #pragma unroll
            for (int mi = 0; mi < 4; ++mi) {
                #pragma unroll
                for (int j = 0; j < 4; ++j) {
                    int gm = m0 + wr * 64 + mi * 16 + lg * 4 + j;
                    if (gm < MROWS)
                        fo[(size_t)gm * CH + gn] = acc[mi][ni][j] + bs;
                }
            }
        }
    }
}

// ---------------- MFMA flash attention ----------------
// grid (10, 192): x -> q-block (reversed: longest first), y -> b*H+h.
// 4 waves, each owns 16 q-rows of the 64-row q-tile. S tile 64x64 per k-tile.
__global__ __launch_bounds__(256) void attn_mfma_k(
    const unsigned short* __restrict__ qg,   // (192, NP, 64) bf16, pre-scaled
    const unsigned short* __restrict__ kg,   // (192, NP, 64) bf16
    const unsigned short* __restrict__ vtg,  // (192, 64, NP) bf16
    const unsigned short* __restrict__ biasg,// (12, 577, 577) bf16
    unsigned short* __restrict__ out)        // (B*SEQ, CH) bf16
{
    __shared__ unsigned short Qs[64 * 64];
    __shared__ unsigned short Ks[64 * 64];
    __shared__ unsigned short VTs[64 * 64];
    __shared__ unsigned short Ps[64 * 64];

    const int qb = 9 - blockIdx.x;
    const int bh = blockIdx.y;
    const int b = bh / NH, h = bh % NH;
    const int t = threadIdx.x;
    const int wid = t >> 6;
    const int lane = t & 63;
    const int lr = lane & 15, lg = lane >> 4;
    const int q0 = qb * 64;

    const size_t kvbase = (size_t)bh * NP * HD;
    const size_t vtbase = (size_t)bh * HD * NP;

    // stage Q (pre-swizzled global source -> linear LDS; swizzle g^=(row&7))
    #pragma unroll
    for (int r = 0; r < 2; ++r) {
        int c = t + r * 256;
        int row = c >> 3, gsrc = (c & 7) ^ (row & 7);
        __builtin_amdgcn_global_load_lds(
            (gp_t)(const void*)(qg + kvbase + (size_t)(q0 + row) * HD + gsrc * 8),
            (lp_t)(void*)(Qs + c * 8), 16, 0, 0);
    }

    f32x4 o_acc[4] = {};
    float m_j[4], l_j[4];
    #pragma unroll
    for (int j = 0; j < 4; ++j) { m_j[j] = -3.0e38f; l_j[j] = 0.f; }

    const int qrow0 = q0 + wid * 16 + lg * 4;

    for (int kb = 0; kb <= qb; ++kb) {
        const int k0 = kb * 64;
        __syncthreads();   // prev tile fully consumed (incl. Q on first pass)
        #pragma unroll
        for (int r = 0; r < 2; ++r) {
            int c = t + r * 256;
            int row = c >> 3, gsrc = (c & 7) ^ (row & 7);
            __builtin_amdgcn_global_load_lds(
                (gp_t)(const void*)(kg + kvbase + (size_t)(k0 + row) * HD + gsrc * 8),
                (lp_t)(void*)(Ks + c * 8), 16, 0, 0);
        }
        #pragma unroll
        for (int r = 0; r < 2; ++r) {
            int c = t + r * 256;
            int row = c >> 3, gsrc = (c & 7) ^ (row & 7);
            __builtin_amdgcn_global_load_lds(
                (gp_t)(const void*)(vtg + vtbase + (size_t)row * NP + k0 + gsrc * 8),
                (lp_t)(void*)(VTs + c * 8), 16, 0, 0);
        }
        __syncthreads();   // tiles landed

        // ---- S = Q K^T (per wave: 16 q-rows x 64 k-cols) ----
        f32x4 s_acc[4] = {};
        #pragma unroll
        for (int kh = 0; kh < 2; ++kh) {
            const int arow = wid * 16 + lr;
            bf16x8 aq = *(const bf16x8*)(Qs + arow * 64 + ((((kh << 2) | lg)) ^ (arow & 7)) * 8);
            #pragma unroll
            for (int ni = 0; ni < 4; ++ni) {
                const int brow = ni * 16 + lr;
                bf16x8 bk = *(const bf16x8*)(Ks + brow * 64 + ((((kh << 2) | lg)) ^ (brow & 7)) * 8);
                s_acc[ni] = __builtin_amdgcn_mfma_f32_16x16x32_bf16(aq, bk, s_acc[ni], 0, 0, 0);
            }
        }

        // ---- bias + causal mask + online softmax (in-register, butterfly over lr) ----
        float pv[4][4];   // [ni][j]
        #pragma unroll
        for (int j = 0; j < 4; ++j) {
            const int qrow = qrow0 + j;
            const int qc = qrow < SEQ ? qrow : SEQ - 1;
            float mx = -3.0e38f;
            #pragma unroll
            for (int ni = 0; ni < 4; ++ni) {
                const int kcol = k0 + ni * 16 + lr;
                const int kc = kcol < SEQ ? kcol : SEQ - 1;
                float v = s_acc[ni][j] + bf2f(biasg[((size_t)h * SEQ + qc) * SEQ + kc]);
                if (kcol > qrow) v = -65504.f;
                pv[ni][j] = v;
                mx = fmaxf(mx, v);
            }
            #pragma unroll
            for (int off = 1; off < 16; off <<= 1)
                mx = fmaxf(mx, __shfl_xor(mx, off, 64));
            const float mnew = fmaxf(m_j[j], mx);
            const float f = __expf(m_j[j] - mnew);
            m_j[j] = mnew;
            float sum = 0.f;
            #pragma unroll
            for (int ni = 0; ni < 4; ++ni) {
                float p = __expf(pv[ni][j] - mnew);
                pv[ni][j] = p;
                sum += p;
            }
            #pragma unroll
            for (int off = 1; off < 16; off <<= 1)
                sum += __shfl_xor(sum, off, 64);
            l_j[j] = l_j[j] * f + sum;
            #pragma unroll
            for (int ni = 0; ni < 4; ++ni) o_acc[ni][j] *= f;
        }

        // ---- P -> bf16 -> swizzled LDS ----
        #pragma unroll
        for (int j = 0; j < 4; ++j) {
            const int prow = wid * 16 + lg * 4 + j;
            #pragma unroll
            for (int ni = 0; ni < 4; ++ni) {
                const int col = ni * 16 + lr;
                Ps[prow * 64 + (((col >> 3) ^ (prow & 7)) << 3) + (col & 7)] = f2bf(pv[ni][j]);
            }
        }
        __syncthreads();   // Ps visible

        // ---- O += P V (A from Ps, B from VTs) ----
        #pragma unroll
        for (int kh = 0; kh < 2; ++kh) {
            const int arow = wid * 16 + lr;
            bf16x8 pa = *(const bf16x8*)(Ps + arow * 64 + ((((kh << 2) | lg)) ^ (arow & 7)) * 8);
            #pragma unroll
            for (int ni = 0; ni < 4; ++ni) {
                const int brow = ni * 16 + lr;
                bf16x8 bv = *(const bf16x8*)(VTs + brow * 64 + ((((kh << 2) | lg)) ^ (brow & 7)) * 8);
                o_acc[ni] = __builtin_amdgcn_mfma_f32_16x16x32_bf16(pa, bv, o_acc[ni], 0, 0, 0);
            }
        }
    }

    // ---- epilogue: O / l -> out (bf16, (B*SEQ, CH)) ----
    #pragma unroll
    for (int j = 0; j < 4; ++j) {
        const int qrow = qrow0 + j;
        if (qrow < SEQ) {
            const float inv = 1.0f / l_j[j];
            const size_t base = ((size_t)b * SEQ + qrow) * CH + h * HD;
            #pragma unroll
            for (int ni = 0; ni < 4; ++ni)
                out[base + ni * 16 + lr] = f2bf(o_acc[ni][j] * inv);
        }
    }
}

extern "C" void kernel_launch(void* const* d_in, const int* in_sizes, int n_in,
                              void* d_out, int out_size, void* d_ws, size_t ws_size,
                              hipStream_t stream) {
    const float* x        = (const float*)d_in[0];
    const float* qkv_w    = (const float*)d_in[1];
    const float* qkv_b    = (const float*)d_in[2];
    const float* pos_emb  = (const float*)d_in[3];
    const float* out_w    = (const float*)d_in[4];
    const float* out_b    = (const float*)d_in[5];
    const int*   rel_idx  = (const int*)d_in[6];
    float* out = (float*)d_out;

    const size_t QP = (size_t)BATCH * NH * NP * HD;   // 7,864,320 elems (padded)
    unsigned short* qp  = (unsigned short*)d_ws;
    unsigned short* kp  = qp + QP;
    unsigned short* vp  = kp + QP;
    unsigned short* vt  = vp + QP;
    unsigned short* xb  = vt + QP;                        // x bf16; attn out aliases
    unsigned short* qwt = xb + (size_t)MROWS * CH;
    unsigned short* owt = qwt + (size_t)(3 * CH) * CH;
    unsigned short* bg  = owt + (size_t)CH * CH;          // bias table

    // prep (no pad-memset: pad K-cols are masked to -inf -> P=0 exactly;
    // pad V rows are multiplied by P=0; pad Q rows discarded in epilogue;
    // 0xAA poison is finite bf16, so all arithmetic stays finite.)
    conv_bf16_k<<<(MROWS * CH / 4 + 255) / 256, 256, 0, stream>>>(x, xb, MROWS * CH / 4);
    transpose_bf16_k<<<dim3(3 * CH / 32, CH / 32), 256, 0, stream>>>(qkv_w, qwt, CH, 3 * CH);
    transpose_bf16_k<<<dim3(CH / 32, CH / 32), 256, 0, stream>>>(out_w, owt, CH, CH);
    bias_k<<<(SEQ * SEQ + 255) / 256, 256, 0, stream>>>(pos_emb, rel_idx, bg);

    // K1: qkv (bf16 outputs, padded, q scaled)
    gemm_bf16_k<0><<<dim3(3 * CH / BN, (MROWS + BM - 1) / BM), 256, 0, stream>>>(
        xb, qwt, qkv_b, nullptr, qp, kp, vp, CH);

    // V^T
    vtrans_k<<<dim3(NP / 64, BATCH * NH), 256, 0, stream>>>(vp, vt);

    // K2: attention (bf16 out into xb)
    attn_mfma_k<<<dim3(10, BATCH * NH), 256, 0, stream>>>(qp, kp, vt, bg, xb);

    // K3: projection
    gemm_bf16_k<1><<<dim3(CH / BN, (MROWS + BM - 1) / BM), 256, 0, stream>>>(
        xb, owt, out_b, out, nullptr, nullptr, nullptr, CH);
}

// Round 6
// 188.385 us; speedup vs baseline: 6.1219x; 1.0164x over previous
//
#include <hip/hip_runtime.h>

// EnhanceSelfAttention  B=16, N=577, C=768, H=12, d=64.
// R6: GEMM template -> 2-phase double-buffered prefetch (T3-minimum):
//     STAGE(next tile) issued BEFORE compute(cur), single barrier/iter whose
//     implicit vmcnt(0) is the prefetch drain. LDS 64KB (2 blocks/CU).
//     Attention unchanged from R5.

#define BATCH 16
#define SEQ   577
#define CH    768
#define NH    12
#define HD    64
#define MROWS (BATCH*SEQ)   // 9232
#define NRD   2212
#define NP    640           // padded seq (10 x 64)

#define BM 128
#define BN 128
#define BK 64

typedef __attribute__((ext_vector_type(8))) short bf16x8;
typedef __attribute__((ext_vector_type(4))) float f32x4;
typedef const __attribute__((address_space(1))) unsigned int* gp_t;
typedef __attribute__((address_space(3))) unsigned int* lp_t;

static __device__ __forceinline__ unsigned short f2bf(float f) {
    unsigned int u = __float_as_uint(f);
    u = (u + 0x7FFFu + ((u >> 16) & 1u)) >> 16;
    return (unsigned short)u;
}
static __device__ __forceinline__ float bf2f(unsigned short b) {
    return __uint_as_float(((unsigned int)b) << 16);
}

// ---------- prep: fp32 -> bf16 straight copy (x) ----------
__global__ __launch_bounds__(256) void conv_bf16_k(
    const float* __restrict__ in, unsigned short* __restrict__ out, int n4)
{
    int i = blockIdx.x * 256 + threadIdx.x;
    if (i < n4) {
        float4 v = ((const float4*)in)[i];
        ushort4 o;
        o.x = f2bf(v.x); o.y = f2bf(v.y); o.z = f2bf(v.z); o.w = f2bf(v.w);
        ((ushort4*)out)[i] = o;
    }
}

// ---------- prep: fp32 (K,N) -> bf16 (N,K) transpose ----------
__global__ __launch_bounds__(256) void transpose_bf16_k(
    const float* __restrict__ w, unsigned short* __restrict__ wt, int K, int N)
{
    __shared__ float tile[32][33];
    const int n0 = blockIdx.x * 32, k0 = blockIdx.y * 32;
    const int tx = threadIdx.x & 31, ty = threadIdx.x >> 5;
    #pragma unroll
    for (int i = 0; i < 32; i += 8)
        tile[ty + i][tx] = w[(size_t)(k0 + ty + i) * N + n0 + tx];
    __syncthreads();
    #pragma unroll
    for (int i = 0; i < 32; i += 8)
        wt[(size_t)(n0 + ty + i) * K + k0 + tx] = f2bf(tile[tx][ty + i]);
}

// ---------- prep: bias_bf16[h][q][k] = pos_emb[h, rel_index[q,k]] ----------
__global__ __launch_bounds__(256) void bias_k(
    const float* __restrict__ pos_emb, const int* __restrict__ rel_index,
    unsigned short* __restrict__ biasg)
{
    int i = blockIdx.x * 256 + threadIdx.x;
    if (i < SEQ * SEQ) {
        int idx = rel_index[i];
        #pragma unroll
        for (int h = 0; h < NH; ++h)
            biasg[(size_t)h * SEQ * SEQ + i] = f2bf(pos_emb[h * NRD + idx]);
    }
}

// ---------- prep: v (bh, NP, 64) -> vt (bh, 64, NP) ----------
__global__ __launch_bounds__(256) void vtrans_k(
    const unsigned short* __restrict__ v, unsigned short* __restrict__ vt)
{
    __shared__ unsigned short tile[64][68];
    const int bh = blockIdx.y;
    const int n0 = blockIdx.x * 64;
    const int tx = threadIdx.x & 7;   // 8 cols of 8
    const int ty = threadIdx.x >> 3;  // 32 rows
    const unsigned short* src = v + ((size_t)bh * NP + n0) * HD;
    #pragma unroll
    for (int i = 0; i < 2; ++i) {
        int r = ty + i * 32;
        *(bf16x8*)&tile[r][tx * 8] = *(const bf16x8*)(src + (size_t)r * HD + tx * 8);
    }
    __syncthreads();
    unsigned short* dst = vt + (size_t)bh * HD * NP + n0;
    #pragma unroll
    for (int i = 0; i < 2; ++i) {
        int d = ty + i * 32;
        bf16x8 o;
        #pragma unroll
        for (int e = 0; e < 8; ++e) o[e] = (short)tile[tx * 8 + e][d];
        *(bf16x8*)(dst + (size_t)d * NP + tx * 8) = o;
    }
}

// ---------- bf16 MFMA GEMM (T2-swizzled LDS + 2-phase dbuf prefetch) ----------
// MODE 0: QKV -> bf16 q/k/v scatter, padded (bh, NP, 64), q pre-scaled 0.125.
// MODE 1: plain fp32 (M,N) + bias.
template<int MODE>
__global__ __launch_bounds__(256) void gemm_bf16_k(
    const unsigned short* __restrict__ A, const unsigned short* __restrict__ Bt,
    const float* __restrict__ bias, float* __restrict__ fo,
    unsigned short* __restrict__ qo, unsigned short* __restrict__ ko,
    unsigned short* __restrict__ vo, int Kdim)
{
    __shared__ unsigned short Asm[2][BM * BK];
    __shared__ unsigned short Bsm[2][BN * BK];
    const int t = threadIdx.x;
    const int wid = t >> 6, lane = t & 63;
    const int m0 = blockIdx.y * BM;
    const int n0 = blockIdx.x * BN;
    const int wr = wid >> 1, wc = wid & 1;
    const int lr = lane & 15, lg = lane >> 4;
    const int swz = lr & 7;

    // per-thread staging coords (hoisted)
    int srowA[4], ssegA[4];
    #pragma unroll
    for (int r = 0; r < 4; ++r) {
        int c = t + r * 256;
        srowA[r] = c >> 3;
        ssegA[r] = (c & 7) ^ ((c >> 3) & 7);   // pre-swizzled source granule
    }

    f32x4 acc[4][4] = {};

    auto stage = [&](int buf, int k0) {
        #pragma unroll
        for (int r = 0; r < 4; ++r) {
            int c = t + r * 256;
            int gm = m0 + srowA[r]; gm = gm < MROWS ? gm : MROWS - 1;
            __builtin_amdgcn_global_load_lds(
                (gp_t)(const void*)(A + (size_t)gm * Kdim + k0 + ssegA[r] * 8),
                (lp_t)(void*)(Asm[buf] + c * 8), 16, 0, 0);
        }
        #pragma unroll
        for (int r = 0; r < 4; ++r) {
            int c = t + r * 256;
            __builtin_amdgcn_global_load_lds(
                (gp_t)(const void*)(Bt + (size_t)(n0 + srowA[r]) * Kdim + k0 + ssegA[r] * 8),
                (lp_t)(void*)(Bsm[buf] + c * 8), 16, 0, 0);
        }
    };

    stage(0, 0);
    __syncthreads();                     // prologue drain (vmcnt(0) implicit)

    const int NT = Kdim / BK;
    int cur = 0;
    for (int tt = 0; tt < NT; ++tt) {
        if (tt + 1 < NT) stage(cur ^ 1, (tt + 1) * BK);   // prefetch next tile

        const unsigned short* Arow0 = Asm[cur] + (wr * 64 + lr) * BK;
        const unsigned short* Brow0 = Bsm[cur] + (wc * 64 + lr) * BK;
        #pragma unroll
        for (int kh = 0; kh < 2; ++kh) {
            const int goff = (((kh << 2) | lg) ^ swz) * 8;   // swizzled granule
            bf16x8 af[4], bfr[4];
            #pragma unroll
            for (int mi = 0; mi < 4; ++mi)
                af[mi] = *(const bf16x8*)(Arow0 + mi * 16 * BK + goff);
            #pragma unroll
            for (int ni = 0; ni < 4; ++ni)
                bfr[ni] = *(const bf16x8*)(Brow0 + ni * 16 * BK + goff);
            #pragma unroll
            for (int mi = 0; mi < 4; ++mi)
                #pragma unroll
                for (int ni = 0; ni < 4; ++ni)
                    acc[mi][ni] = __builtin_amdgcn_mfma_f32_16x16x32_bf16(
                        af[mi], bfr[ni], acc[mi][ni], 0, 0, 0);
        }
        __syncthreads();   // single barrier/iter: drains prefetch (vmcnt(0)) + syncs
        cur ^= 1;
    }

    if (MODE == 0) {
        // hoisted row decomposition (independent of ni)
        int rbase[16];
        #pragma unroll
        for (int mi = 0; mi < 4; ++mi) {
            #pragma unroll
            for (int j = 0; j < 4; ++j) {
                int gm = m0 + wr * 64 + mi * 16 + lg * 4 + j;
                int bb = gm / SEQ, ss = gm - bb * SEQ;
                rbase[mi * 4 + j] = (gm < MROWS) ? (bb * NH * NP + ss) : -1;
            }
        }
        #pragma unroll
        for (int ni = 0; ni < 4; ++ni) {
            const int gn = n0 + wc * 64 + ni * 16 + lr;
            const float bs = bias[gn];
            const int i3 = gn / CH;
            const int hh = (gn % CH) / HD;
            const int dd = gn % HD;
            unsigned short* dst = (i3 == 0) ? qo : (i3 == 1) ? ko : vo;
            const float scl = (i3 == 0) ? 0.125f : 1.0f;
            #pragma unroll
            for (int mi = 0; mi < 4; ++mi) {
                #pragma unroll
                for (int j = 0; j < 4; ++j) {
                    int rb = rbase[mi * 4 + j];
                    if (rb >= 0)
                        dst[((size_t)rb + (size_t)hh * NP) * HD + dd] =
                            f2bf((acc[mi][ni][j] + bs) * scl);
                }
            }
        }
    } else {
        #pragma unroll
        for (int ni = 0; ni < 4; ++ni) {
            const int gn = n0 + wc * 64 + ni * 16 + lr;
            const float bs = bias[gn];
            #pragma unroll
            for (int mi = 0; mi < 4; ++mi) {
                #pragma unroll
                for (int j = 0; j < 4; ++j) {
                    int gm = m0 + wr * 64 + mi * 16 + lg * 4 + j;
                    if (gm < MROWS)
                        fo[(size_t)gm * CH + gn] = acc[mi][ni][j] + bs;
                }
            }
        }
    }
}

// ---------------- MFMA flash attention (unchanged from R5) ----------------
__global__ __launch_bounds__(256) void attn_mfma_k(
    const unsigned short* __restrict__ qg,   // (192, NP, 64) bf16, pre-scaled
    const unsigned short* __restrict__ kg,   // (192, NP, 64) bf16
    const unsigned short* __restrict__ vtg,  // (192, 64, NP) bf16
    const unsigned short* __restrict__ biasg,// (12, 577, 577) bf16
    unsigned short* __restrict__ out)        // (B*SEQ, CH) bf16
{
    __shared__ unsigned short Qs[64 * 64];
    __shared__ unsigned short Ks[64 * 64];
    __shared__ unsigned short VTs[64 * 64];
    __shared__ unsigned short Ps[64 * 64];

    const int qb = 9 - blockIdx.x;
    const int bh = blockIdx.y;
    const int b = bh / NH, h = bh % NH;
    const int t = threadIdx.x;
    const int wid = t >> 6;
    const int lane = t & 63;
    const int lr = lane & 15, lg = lane >> 4;
    const int q0 = qb * 64;

    const size_t kvbase = (size_t)bh * NP * HD;
    const size_t vtbase = (size_t)bh * HD * NP;

    // stage Q (pre-swizzled global source -> linear LDS; swizzle g^=(row&7))
    #pragma unroll
    for (int r = 0; r < 2; ++r) {
        int c = t + r * 256;
        int row = c >> 3, gsrc = (c & 7) ^ (row & 7);
        __builtin_amdgcn_global_load_lds(
            (gp_t)(const void*)(qg + kvbase + (size_t)(q0 + row) * HD + gsrc * 8),
            (lp_t)(void*)(Qs + c * 8), 16, 0, 0);
    }

    f32x4 o_acc[4] = {};
    float m_j[4], l_j[4];
    #pragma unroll
    for (int j = 0; j < 4; ++j) { m_j[j] = -3.0e38f; l_j[j] = 0.f; }

    const int qrow0 = q0 + wid * 16 + lg * 4;

    for (int kb = 0; kb <= qb; ++kb) {
        const int k0 = kb * 64;
        __syncthreads();   // prev tile fully consumed (incl. Q on first pass)
        #pragma unroll
        for (int r = 0; r < 2; ++r) {
            int c = t + r * 256;
            int row = c >> 3, gsrc = (c & 7) ^ (row & 7);
            __builtin_amdgcn_global_load_lds(
                (gp_t)(const void*)(kg + kvbase + (size_t)(k0 + row) * HD + gsrc * 8),
                (lp_t)(void*)(Ks + c * 8), 16, 0, 0);
        }
        #pragma unroll
        for (int r = 0; r < 2; ++r) {
            int c = t + r * 256;
            int row = c >> 3, gsrc = (c & 7) ^ (row & 7);
            __builtin_amdgcn_global_load_lds(
                (gp_t)(const void*)(vtg + vtbase + (size_t)row * NP + k0 + gsrc * 8),
                (lp_t)(void*)(VTs + c * 8), 16, 0, 0);
        }
        __syncthreads();   // tiles landed

        // ---- S = Q K^T (per wave: 16 q-rows x 64 k-cols) ----
        f32x4 s_acc[4] = {};
        #pragma unroll
        for (int kh = 0; kh < 2; ++kh) {
            const int arow = wid * 16 + lr;
            bf16x8 aq = *(const bf16x8*)(Qs + arow * 64 + ((((kh << 2) | lg)) ^ (arow & 7)) * 8);
            #pragma unroll
            for (int ni = 0; ni < 4; ++ni) {
                const int brow = ni * 16 + lr;
                bf16x8 bk = *(const bf16x8*)(Ks + brow * 64 + ((((kh << 2) | lg)) ^ (brow & 7)) * 8);
                s_acc[ni] = __builtin_amdgcn_mfma_f32_16x16x32_bf16(aq, bk, s_acc[ni], 0, 0, 0);
            }
        }

        // ---- bias + causal mask + online softmax (in-register, butterfly over lr) ----
        float pv[4][4];   // [ni][j]
        #pragma unroll
        for (int j = 0; j < 4; ++j) {
            const int qrow = qrow0 + j;
            const int qc = qrow < SEQ ? qrow : SEQ - 1;
            float mx = -3.0e38f;
            #pragma unroll
            for (int ni = 0; ni < 4; ++ni) {
                const int kcol = k0 + ni * 16 + lr;
                const int kc = kcol < SEQ ? kcol : SEQ - 1;
                float v = s_acc[ni][j] + bf2f(biasg[((size_t)h * SEQ + qc) * SEQ + kc]);
                if (kcol > qrow) v = -65504.f;
                pv[ni][j] = v;
                mx = fmaxf(mx, v);
            }
            #pragma unroll
            for (int off = 1; off < 16; off <<= 1)
                mx = fmaxf(mx, __shfl_xor(mx, off, 64));
            const float mnew = fmaxf(m_j[j], mx);
            const float f = __expf(m_j[j] - mnew);
            m_j[j] = mnew;
            float sum = 0.f;
            #pragma unroll
            for (int ni = 0; ni < 4; ++ni) {
                float p = __expf(pv[ni][j] - mnew);
                pv[ni][j] = p;
                sum += p;
            }
            #pragma unroll
            for (int off = 1; off < 16; off <<= 1)
                sum += __shfl_xor(sum, off, 64);
            l_j[j] = l_j[j] * f + sum;
            #pragma unroll
            for (int ni = 0; ni < 4; ++ni) o_acc[ni][j] *= f;
        }

        // ---- P -> bf16 -> swizzled LDS ----
        #pragma unroll
        for (int j = 0; j < 4; ++j) {
            const int prow = wid * 16 + lg * 4 + j;
            #pragma unroll
            for (int ni = 0; ni < 4; ++ni) {
                const int col = ni * 16 + lr;
                Ps[prow * 64 + (((col >> 3) ^ (prow & 7)) << 3) + (col & 7)] = f2bf(pv[ni][j]);
            }
        }
        __syncthreads();   // Ps visible

        // ---- O += P V (A from Ps, B from VTs) ----
        #pragma unroll
        for (int kh = 0; kh < 2; ++kh) {
            const int arow = wid * 16 + lr;
            bf16x8 pa = *(const bf16x8*)(Ps + arow * 64 + ((((kh << 2) | lg)) ^ (arow & 7)) * 8);
            #pragma unroll
            for (int ni = 0; ni < 4; ++ni) {
                const int brow = ni * 16 + lr;
                bf16x8 bv = *(const bf16x8*)(VTs + brow * 64 + ((((kh << 2) | lg)) ^ (brow & 7)) * 8);
                o_acc[ni] = __builtin_amdgcn_mfma_f32_16x16x32_bf16(pa, bv, o_acc[ni], 0, 0, 0);
            }
        }
    }

    // ---- epilogue: O / l -> out (bf16, (B*SEQ, CH)) ----
    #pragma unroll
    for (int j = 0; j < 4; ++j) {
        const int qrow = qrow0 + j;
        if (qrow < SEQ) {
            const float inv = 1.0f / l_j[j];
            const size_t base = ((size_t)b * SEQ + qrow) * CH + h * HD;
            #pragma unroll
            for (int ni = 0; ni < 4; ++ni)
                out[base + ni * 16 + lr] = f2bf(o_acc[ni][j] * inv);
        }
    }
}

extern "C" void kernel_launch(void* const* d_in, const int* in_sizes, int n_in,
                              void* d_out, int out_size, void* d_ws, size_t ws_size,
                              hipStream_t stream) {
    const float* x        = (const float*)d_in[0];
    const float* qkv_w    = (const float*)d_in[1];
    const float* qkv_b    = (const float*)d_in[2];
    const float* pos_emb  = (const float*)d_in[3];
    const float* out_w    = (const float*)d_in[4];
    const float* out_b    = (const float*)d_in[5];
    const int*   rel_idx  = (const int*)d_in[6];
    float* out = (float*)d_out;

    const size_t QP = (size_t)BATCH * NH * NP * HD;   // 7,864,320 elems (padded)
    unsigned short* qp  = (unsigned short*)d_ws;
    unsigned short* kp  = qp + QP;
    unsigned short* vp  = kp + QP;
    unsigned short* vt  = vp + QP;
    unsigned short* xb  = vt + QP;                        // x bf16; attn out aliases
    unsigned short* qwt = xb + (size_t)MROWS * CH;
    unsigned short* owt = qwt + (size_t)(3 * CH) * CH;
    unsigned short* bg  = owt + (size_t)CH * CH;          // bias table

    // prep (no pad-memset: pad K-cols masked to -inf -> P=0; pad V rows
    // weighted by P=0; pad Q rows discarded; 0xAA poison is finite bf16.)
    conv_bf16_k<<<(MROWS * CH / 4 + 255) / 256, 256, 0, stream>>>(x, xb, MROWS * CH / 4);
    transpose_bf16_k<<<dim3(3 * CH / 32, CH / 32), 256, 0, stream>>>(qkv_w, qwt, CH, 3 * CH);
    transpose_bf16_k<<<dim3(CH / 32, CH / 32), 256, 0, stream>>>(out_w, owt, CH, CH);
    bias_k<<<(SEQ * SEQ + 255) / 256, 256, 0, stream>>>(pos_emb, rel_idx, bg);

    // K1: qkv (bf16 outputs, padded, q scaled)
    gemm_bf16_k<0><<<dim3(3 * CH / BN, (MROWS + BM - 1) / BM), 256, 0, stream>>>(
        xb, qwt, qkv_b, nullptr, qp, kp, vp, CH);

    // V^T
    vtrans_k<<<dim3(NP / 64, BATCH * NH), 256, 0, stream>>>(vp, vt);

    // K2: attention (bf16 out into xb)
    attn_mfma_k<<<dim3(10, BATCH * NH), 256, 0, stream>>>(qp, kp, vt, bg, xb);

    // K3: projection
    gemm_bf16_k<1><<<dim3(CH / BN, (MROWS + BM - 1) / BM), 256, 0, stream>>>(
        xb, owt, out_b, out, nullptr, nullptr, nullptr, CH);
}